// Round 10
// baseline (937.219 us; speedup 1.0000x reference)
//
#include <hip/hip_runtime.h>

// ---------------------------------------------------------------------------
// Seq2Seq: encoder LSTM (128 steps) -> decoder LSTM (127 steps) -> FC to vocab
// B=32, S=T=128, V=32000, E=H=256
//
// R10: fuse decoder+FC. One 256-block kernel (1 block/CU via 132KB LDS):
//  blocks 0..31  = LSTM producers (R9 dataflow, unchanged): publish
//                  prog[b]=chunk (32 decoder steps) via threadfence + agent
//                  release store -- 4 publishes per chain.
//  blocks 32..255 = FC consumers: pull (tc,b,nb) tiles (32x128) from a global
//                  atomic counter, spin on prog[b] (relaxed + final acquire),
//                  MFMA, transpose through LDS, full-512B-segment nt stores.
//  Producers join consumption after their chains finish (tail balancing).
// FC's ~93us of HBM-write work hides under the decoder's ~220us.
// ---------------------------------------------------------------------------

typedef __attribute__((ext_vector_type(8))) short bf16x8;
typedef __attribute__((ext_vector_type(4))) float f32x4;
typedef __attribute__((ext_vector_type(8))) unsigned short u16x8;
typedef __attribute__((ext_vector_type(4))) unsigned int u32x4;
typedef __attribute__((ext_vector_type(8))) _Float16 f16x8;
typedef __attribute__((ext_vector_type(2))) _Float16 h2;

// workspace byte offsets (all 256-aligned)
#define WS_XG_E   0u          // 128*32*1024 f32 = 16,777,216 B
#define WS_XG_D   16777216u   // 127*32*1024 f32 = 16,646,144 B
#define WS_FCW    33423360u   // 32000*256 bf16  = 16,384,000 B
#define WS_HS     49807360u   // 4096*256 bf16   =  2,097,152 B (padded [b*128+t])
#define WS_WTE    51904512u   // 1024*256 f16    =    524,288 B
#define WS_WTD    52428800u   // 1024*256 f16    =    524,288 B
#define WS_FLAGS  52953088u   // prog[32] + ctr  =        256 B

#define KC_REG 48   // weight chunks in registers (gates i,f,g)
#define KC_LDS 16   // weight chunks in LDS (gate o) = 128 KB

#define N_TILES 32000   // 4 tc * 32 b * 250 nb

__device__ __forceinline__ unsigned short f2bf(float f) {
  unsigned u = __float_as_uint(f);
  u += 0x7FFFu + ((u >> 16) & 1u);   // round-to-nearest-even
  return (unsigned short)(u >> 16);
}

__device__ __forceinline__ float sigf(float x) {
  float e = __expf(-x);
  return __builtin_amdgcn_rcpf(1.f + e);
}
__device__ __forceinline__ float tanh_fast(float x) {
  float e = __expf(-2.f * x);
  return fmaf(2.f, __builtin_amdgcn_rcpf(1.f + e), -1.f);  // (1-e)/(1+e)
}

#if __has_builtin(__builtin_amdgcn_fdot2)
#define FDOT2(a, w, h) a = __builtin_amdgcn_fdot2(w, h, a, false)
#else
#define FDOT2(a, w, h) a = fmaf((float)w[0], (float)h[0], fmaf((float)w[1], (float)h[1], a))
#endif

// 8 f16 weights vs 8 f16 h values -> two accumulator chains
__device__ __forceinline__ void dot8(const u16x8 w, const u32x4 hbits,
                                     float& a0, float& a1) {
  f16x8 wv = __builtin_bit_cast(f16x8, w);
  f16x8 hv = __builtin_bit_cast(f16x8, hbits);
  h2 w0 = {wv[0], wv[1]}, w1 = {wv[2], wv[3]};
  h2 w2 = {wv[4], wv[5]}, w3 = {wv[6], wv[7]};
  h2 h0 = {hv[0], hv[1]}, h1 = {hv[2], hv[3]};
  h2 hc = {hv[4], hv[5]}, h3 = {hv[6], hv[7]};
  FDOT2(a0, w0, h0);
  FDOT2(a1, w1, h1);
  FDOT2(a0, w2, hc);
  FDOT2(a1, w3, h3);
}

// ---------------------------------------------------------------------------
__global__ __launch_bounds__(256) void zero_col0(float* __restrict__ out) {
  int i = blockIdx.x * 256 + threadIdx.x;        // 256,000 float4s total
  int b = i / 8000;
  int r = i - b * 8000;
  f32x4 z = {0.f, 0.f, 0.f, 0.f};
  __builtin_nontemporal_store(z, (f32x4*)out + b * 1024000 + r);
}

__global__ __launch_bounds__(256) void cvt_bf16(const float* __restrict__ in,
                                                unsigned short* __restrict__ o,
                                                int n4) {
  int i = blockIdx.x * 256 + threadIdx.x;
  if (i < n4) {
    float4 v = ((const float4*)in)[i];
    ushort4 u;
    u.x = f2bf(v.x); u.y = f2bf(v.y); u.z = f2bf(v.z); u.w = f2bf(v.w);
    *(ushort4*)(o + i * 4) = u;
  }
}

// Whh[1024 r][256 k] -> f16 T[chunk j][512 tid][8 e], j = gate*16 + kk.
__global__ __launch_bounds__(256) void prep_whalf(const float* __restrict__ We,
                                                  const float* __restrict__ Wd,
                                                  unsigned short* __restrict__ Te,
                                                  unsigned short* __restrict__ Td) {
  int d = blockIdx.x * 256 + threadIdx.x;       // 0..262143
  const float* W = blockIdx.y ? Wd : We;
  unsigned short* T = blockIdx.y ? Td : Te;
  int e = d & 7;
  int tmp = d >> 3;
  int tidb = tmp & 511;
  int j = tmp >> 9;                 // 0..63
  int gg = j >> 4, kk = j & 15;
  int wv = tidb >> 6, ln = tidb & 63;
  int qq = ln >> 5, dm = wv * 32 + (ln & 31);
  _Float16 v = (_Float16)W[(gg * 256 + dm) * 256 + qq * 128 + kk * 8 + e];
  T[d] = __builtin_bit_cast(unsigned short, v);
}

// ---------------------------------------------------------------------------
// xg[row][n] = emb[token(row)] @ Wih^T + bias ; row = t*32 + b
__global__ __launch_bounds__(256) void xg_gemm(
    const int* __restrict__ tok, const float* __restrict__ emb,
    const float* __restrict__ Wih, const float* __restrict__ bias,
    float* __restrict__ xg, const int Mrows) {
  __shared__ unsigned short As[128][264];  // +8 bf16 pad -> 2-way (free)
  __shared__ unsigned short Bs[128][264];
  const int tid = threadIdx.x;
  const int nb = blockIdx.x, rb = blockIdx.y;
  {
    int lr = tid >> 1, half = tid & 1;
    int cb = half * 128;
    int row = rb * 128 + lr;
    int rowc = row < Mrows ? row : (Mrows - 1);
    int tt = rowc >> 5, bb = rowc & 31;
    int tk = tok[bb * 128 + tt];
    const float4* sa = (const float4*)(emb + tk * 256 + cb);
    const float4* sb = (const float4*)(Wih + (nb * 128 + lr) * 256 + cb);
#pragma unroll
    for (int i = 0; i < 32; ++i) {
      float4 v = sa[i];
      ushort4 u;
      u.x = f2bf(v.x); u.y = f2bf(v.y); u.z = f2bf(v.z); u.w = f2bf(v.w);
      *(ushort4*)&As[lr][cb + i * 4] = u;
      float4 v2 = sb[i];
      ushort4 u2;
      u2.x = f2bf(v2.x); u2.y = f2bf(v2.y); u2.z = f2bf(v2.z); u2.w = f2bf(v2.w);
      *(ushort4*)&Bs[lr][cb + i * 4] = u2;
    }
  }
  __syncthreads();
  const int lane = tid & 63, w = tid >> 6;
  const int wr = w >> 1, wc = w & 1;
  const int fr = lane & 15, kg = lane >> 4;
  f32x4 acc[4][4];
  const f32x4 zero = {0.f, 0.f, 0.f, 0.f};
#pragma unroll
  for (int mi = 0; mi < 4; ++mi)
#pragma unroll
    for (int ni = 0; ni < 4; ++ni) acc[mi][ni] = zero;
#pragma unroll
  for (int ks = 0; ks < 8; ++ks) {
    const int kb = ks * 32 + kg * 8;
    bf16x8 a[4], b[4];
#pragma unroll
    for (int mi = 0; mi < 4; ++mi)
      a[mi] = *(const bf16x8*)&As[wr * 64 + mi * 16 + fr][kb];
#pragma unroll
    for (int ni = 0; ni < 4; ++ni)
      b[ni] = *(const bf16x8*)&Bs[wc * 64 + ni * 16 + fr][kb];
#pragma unroll
    for (int mi = 0; mi < 4; ++mi)
#pragma unroll
      for (int ni = 0; ni < 4; ++ni)
        acc[mi][ni] = __builtin_amdgcn_mfma_f32_16x16x32_bf16(a[mi], b[ni], acc[mi][ni], 0, 0, 0);
  }
#pragma unroll
  for (int ni = 0; ni < 4; ++ni) {
    const int colg = nb * 128 + wc * 64 + ni * 16 + fr;
    const float bv = bias[colg];
#pragma unroll
    for (int mi = 0; mi < 4; ++mi) {
#pragma unroll
      for (int r = 0; r < 4; ++r) {
        int rowg = rb * 128 + wr * 64 + mi * 16 + kg * 4 + r;
        if (rowg < Mrows) xg[rowg * 1024 + colg] = acc[mi][ni][r] + bv;
      }
    }
  }
}

// ---------------------------------------------------------------------------
// Fused LSTM producers + FC consumers. 256 blocks x 512 threads, 1 block/CU.
__global__ __launch_bounds__(512, 2) void lstm_fc(
    const unsigned short* __restrict__ WTe, const unsigned short* __restrict__ WTd,
    const float* __restrict__ xgE, const float* __restrict__ xgD,
    unsigned short* __restrict__ hs, const unsigned short* __restrict__ fwb,
    const float* __restrict__ fcb, float* __restrict__ out,
    unsigned* __restrict__ flags) {
  __shared__ __align__(16) char smem[132096];
  __shared__ int curid;
  const int tid = threadIdx.x;   // 0..511
  const int blk = blockIdx.x;
  unsigned* prog = flags;        // [32] chunks published per batch row
  unsigned* ctr = flags + 32;    // tile counter

  if (blk < 32) {
    // ================= producer: LSTM chain for batch row blk ==============
    unsigned short (*hh)[256] = (unsigned short (*)[256])smem;  // dbuf h f16
    unsigned short* wl = (unsigned short*)(smem + 1024);        // 128 KB o-gate
    const int b = blk;
    const int l = tid & 63, w = tid >> 6;
    const int q = l >> 5;
    const int dim = w * 32 + (l & 31);
    float c = 0.f;
    int cur = 0;
    if (tid < 256) hh[0][tid] = 0;

    for (int phase = 0; phase < 2; ++phase) {
      const unsigned short* WT = phase ? WTd : WTe;
      const float* xg = phase ? xgD : xgE;
      const int steps = phase ? 127 : 128;
      const u16x8* wsrc = (const u16x8*)WT + tid;
      u16x8 wr[KC_REG];
#pragma unroll
      for (int j = 0; j < KC_REG; ++j) wr[j] = wsrc[j * 512];
      __syncthreads();
      {
        u16x8* ld = (u16x8*)wl + tid;
#pragma unroll
        for (int j = 0; j < KC_LDS; ++j) ld[j * 512] = wsrc[(KC_REG + j) * 512];
      }
      __syncthreads();

      for (int t = 0; t < steps; ++t) {
        const float* xr = xg + (t * 32 + b) * 1024 + dim;
        float x0 = xr[0], x1 = xr[256], x2 = xr[512], x3 = xr[768];
        const u32x4* hq = (const u32x4*)&hh[cur][q * 128];
        const u16x8* wlp = (const u16x8*)wl + tid;
        float ai0 = 0.f, ai1 = 0.f, af0 = 0.f, af1 = 0.f;
        float ag0 = 0.f, ag1 = 0.f, ao0 = 0.f, ao1 = 0.f;
#pragma unroll
        for (int kk = 0; kk < 16; ++kk) {
          u32x4 hv = hq[kk];
          dot8(wr[kk],        hv, ai0, ai1);
          dot8(wr[16 + kk],   hv, af0, af1);
          dot8(wr[32 + kk],   hv, ag0, ag1);
          dot8(wlp[kk * 512], hv, ao0, ao1);
        }
        float gi = ai0 + ai1, gf = af0 + af1;
        float gg = ag0 + ag1, go = ao0 + ao1;
        gi += __shfl_xor(gi, 32, 64);
        gf += __shfl_xor(gf, 32, 64);
        gg += __shfl_xor(gg, 32, 64);
        go += __shfl_xor(go, 32, 64);
        gi += x0; gf += x1; gg += x2; go += x3;
        c = sigf(gf) * c + sigf(gi) * tanh_fast(gg);
        float h = sigf(go) * tanh_fast(c);
        if (l < 32) {
          _Float16 hf = (_Float16)h;
          hh[cur ^ 1][dim] = __builtin_bit_cast(unsigned short, hf);
          if (phase) hs[(b * 128 + t) * 256 + dim] = f2bf(h);
        }
        __syncthreads();               // h(t) + hs stores complete (vmcnt 0)
        cur ^= 1;
        if (phase && (((t & 31) == 31) || (t == 126))) {
          if (tid == 0) {
            __threadfence();           // agent fence: flush hs to coherent pt
            __hip_atomic_store(&prog[b], (unsigned)((t >> 5) + 1),
                               __ATOMIC_RELEASE, __HIP_MEMORY_SCOPE_AGENT);
          }
        }
      }
    }
  }

  // ================= consumer: FC tiles (all blocks join) ==================
  typedef unsigned short usrow[264];
  usrow* Bs = (usrow*)smem;                       // [128][264]
  usrow* As = (usrow*)(smem + 67584);             // [32][264]
  typedef float frow[132];
  frow* Ct = (frow*)(smem + 67584);               // [32][132], reuses As
  const int lane = tid & 63, wv = tid >> 6;
  const int wm = wv & 1, wn = wv >> 1;            // 2 m-tiles x 4 n-tiles
  const int fr = lane & 15, kg = lane >> 4;

  while (true) {
    __syncthreads();                   // protect smem + curid from prev iter
    if (tid == 0) {
      curid = (int)__hip_atomic_fetch_add(ctr, 1u, __ATOMIC_RELAXED,
                                          __HIP_MEMORY_SCOPE_AGENT);
    }
    __syncthreads();
    const int id = curid;
    if (id >= N_TILES) break;
    const int tc = id / 8000;
    const int rem = id - tc * 8000;
    const int b = rem / 250, nb = rem - b * 250;
    if (tid == 0) {
      const unsigned need = (unsigned)(tc + 1);
      while (__hip_atomic_load(&prog[b], __ATOMIC_RELAXED,
                               __HIP_MEMORY_SCOPE_AGENT) < need)
        __builtin_amdgcn_s_sleep(8);
      (void)__hip_atomic_load(&prog[b], __ATOMIC_ACQUIRE,
                              __HIP_MEMORY_SCOPE_AGENT);
    }
    __syncthreads();                   // hs chunk visible to whole block
    {                                  // stage B (128x256) and A (32x256)
      int row = tid >> 2, sg = tid & 3;
      const u16x8* s = (const u16x8*)(fwb + (nb * 128 + row) * 256 + sg * 64);
      u16x8* d = (u16x8*)&Bs[row][sg * 64];
#pragma unroll
      for (int i = 0; i < 8; ++i) d[i] = s[i];
      int ar = tid >> 4, ac = (tid & 15) * 16;
      const u16x8* s2 = (const u16x8*)(hs + (b * 128 + tc * 32 + ar) * 256 + ac);
      u16x8* d2 = (u16x8*)&As[ar][ac];
      d2[0] = s2[0]; d2[1] = s2[1];
    }
    __syncthreads();
    f32x4 acc[2];
    const f32x4 zero = {0.f, 0.f, 0.f, 0.f};
    acc[0] = zero; acc[1] = zero;
#pragma unroll
    for (int ks = 0; ks < 8; ++ks) {
      const int kb = ks * 32 + kg * 8;
      bf16x8 a = *(const bf16x8*)&As[wm * 16 + fr][kb];
      bf16x8 b0 = *(const bf16x8*)&Bs[wn * 32 + fr][kb];
      bf16x8 b1 = *(const bf16x8*)&Bs[wn * 32 + 16 + fr][kb];
      acc[0] = __builtin_amdgcn_mfma_f32_16x16x32_bf16(a, b0, acc[0], 0, 0, 0);
      acc[1] = __builtin_amdgcn_mfma_f32_16x16x32_bf16(a, b1, acc[1], 0, 0, 0);
    }
    __syncthreads();                   // done reading As before Ct overwrite
#pragma unroll
    for (int ni = 0; ni < 2; ++ni) {
      const int cl = wn * 32 + ni * 16 + fr;
      const float bv = fcb[nb * 128 + cl];
#pragma unroll
      for (int r = 0; r < 4; ++r)
        Ct[wm * 16 + kg * 4 + r][cl] = acc[ni][r] + bv;
    }
    __syncthreads();
    {                                  // 512B-contiguous nt stores, 2 rows/wave
      int r = tid >> 4, cc = (tid & 15) * 8;
      int tg = tc * 32 + r;
      if (tg != 127) {                 // t=127 is padding
        float* dst = out + (size_t)(b * 128 + tg + 1) * 32000 + nb * 128 + cc;
        f32x4 v0 = *(const f32x4*)&Ct[r][cc];
        f32x4 v1 = *(const f32x4*)&Ct[r][cc + 4];
        __builtin_nontemporal_store(v0, (f32x4*)dst);
        __builtin_nontemporal_store(v1, (f32x4*)(dst + 4));
      }
    }
  }
}

// ---------------------------------------------------------------------------
extern "C" void kernel_launch(void* const* d_in, const int* in_sizes, int n_in,
                              void* d_out, int out_size, void* d_ws, size_t ws_size,
                              hipStream_t stream) {
  const int* src = (const int*)d_in[0];
  const int* tgt = (const int*)d_in[1];
  const float* enc_emb = (const float*)d_in[2];
  const float* enc_Wih = (const float*)d_in[3];
  const float* enc_Whh = (const float*)d_in[4];
  const float* enc_b = (const float*)d_in[5];
  const float* dec_emb = (const float*)d_in[6];
  const float* dec_Wih = (const float*)d_in[7];
  const float* dec_Whh = (const float*)d_in[8];
  const float* dec_b = (const float*)d_in[9];
  const float* fc_W = (const float*)d_in[10];
  const float* fc_b = (const float*)d_in[11];
  float* out = (float*)d_out;
  char* ws = (char*)d_ws;

  float* xg_e = (float*)(ws + WS_XG_E);
  float* xg_d = (float*)(ws + WS_XG_D);
  unsigned short* fcw = (unsigned short*)(ws + WS_FCW);
  unsigned short* hs = (unsigned short*)(ws + WS_HS);
  unsigned short* wte = (unsigned short*)(ws + WS_WTE);
  unsigned short* wtd = (unsigned short*)(ws + WS_WTD);
  unsigned* flags = (unsigned*)(ws + WS_FLAGS);

  hipMemsetAsync(ws + WS_FLAGS, 0, 256, stream);   // prog[32] + ctr = 0
  zero_col0<<<1000, 256, 0, stream>>>(out);
  cvt_bf16<<<8000, 256, 0, stream>>>(fc_W, fcw, 2048000);
  prep_whalf<<<dim3(1024, 2), 256, 0, stream>>>(enc_Whh, dec_Whh, wte, wtd);
  xg_gemm<<<dim3(8, 32), 256, 0, stream>>>(src, enc_emb, enc_Wih, enc_b, xg_e, 4096);
  xg_gemm<<<dim3(8, 32), 256, 0, stream>>>(tgt, dec_emb, dec_Wih, dec_b, xg_d, 4064);
  lstm_fc<<<256, 512, 0, stream>>>(wte, wtd, xg_e, xg_d, hs, fcw, fc_b, out, flags);
}

// Round 11
// 728.372 us; speedup vs baseline: 1.2867x; 1.2867x over previous
//
#include <hip/hip_runtime.h>

// ---------------------------------------------------------------------------
// Seq2Seq: encoder LSTM (128 steps) -> decoder LSTM (127 steps) -> FC to vocab
// B=32, S=T=128, V=32000, E=H=256
//
// R11: fusion v2. R10's consumer was traffic-heavy: per-tile B reload (2.2GB
// L2 traffic) + split nt stores (partial 64B sectors -> RMW, WRITE 740MB).
// Fix: work item = (tc,nb): stage fcw B-tile ONCE, loop all 32 batch rows
// (wait prog[b] -> stage 16KB A -> MFMA -> full-sector stores). B reads
// 2.1GB -> 64MB; stores RMW-free (wave = 2 rows x 512B contiguous / inst).
// Producers (blocks 0..31) run the R9 LSTM chain unchanged, publish prog[b]
// every 32 decoder steps, then join consumption.
// ---------------------------------------------------------------------------

typedef __attribute__((ext_vector_type(8))) short bf16x8;
typedef __attribute__((ext_vector_type(4))) float f32x4;
typedef __attribute__((ext_vector_type(8))) unsigned short u16x8;
typedef __attribute__((ext_vector_type(4))) unsigned int u32x4;
typedef __attribute__((ext_vector_type(8))) _Float16 f16x8;
typedef __attribute__((ext_vector_type(2))) _Float16 h2;

// workspace byte offsets (all 256-aligned)
#define WS_XG_E   0u          // 128*32*1024 f32 = 16,777,216 B
#define WS_XG_D   16777216u   // 127*32*1024 f32 = 16,646,144 B
#define WS_FCW    33423360u   // 32000*256 bf16  = 16,384,000 B
#define WS_HS     49807360u   // 4096*256 bf16   =  2,097,152 B (padded [b*128+t])
#define WS_WTE    51904512u   // 1024*256 f16    =    524,288 B
#define WS_WTD    52428800u   // 1024*256 f16    =    524,288 B
#define WS_FLAGS  52953088u   // prog[32] + ctr  =        256 B

#define KC_REG 48   // weight chunks in registers (gates i,f,g)
#define KC_LDS 16   // weight chunks in LDS (gate o) = 128 KB

#define N_ITEMS 1000   // 4 tc * 250 nb; item stages B once, loops 32 b

__device__ __forceinline__ unsigned short f2bf(float f) {
  unsigned u = __float_as_uint(f);
  u += 0x7FFFu + ((u >> 16) & 1u);   // round-to-nearest-even
  return (unsigned short)(u >> 16);
}

__device__ __forceinline__ float sigf(float x) {
  float e = __expf(-x);
  return __builtin_amdgcn_rcpf(1.f + e);
}
__device__ __forceinline__ float tanh_fast(float x) {
  float e = __expf(-2.f * x);
  return fmaf(2.f, __builtin_amdgcn_rcpf(1.f + e), -1.f);  // (1-e)/(1+e)
}

#if __has_builtin(__builtin_amdgcn_fdot2)
#define FDOT2(a, w, h) a = __builtin_amdgcn_fdot2(w, h, a, false)
#else
#define FDOT2(a, w, h) a = fmaf((float)w[0], (float)h[0], fmaf((float)w[1], (float)h[1], a))
#endif

// 8 f16 weights vs 8 f16 h values -> two accumulator chains
__device__ __forceinline__ void dot8(const u16x8 w, const u32x4 hbits,
                                     float& a0, float& a1) {
  f16x8 wv = __builtin_bit_cast(f16x8, w);
  f16x8 hv = __builtin_bit_cast(f16x8, hbits);
  h2 w0 = {wv[0], wv[1]}, w1 = {wv[2], wv[3]};
  h2 w2 = {wv[4], wv[5]}, w3 = {wv[6], wv[7]};
  h2 h0 = {hv[0], hv[1]}, h1 = {hv[2], hv[3]};
  h2 hc = {hv[4], hv[5]}, h3 = {hv[6], hv[7]};
  FDOT2(a0, w0, h0);
  FDOT2(a1, w1, h1);
  FDOT2(a0, w2, hc);
  FDOT2(a1, w3, h3);
}

// ---------------------------------------------------------------------------
__global__ __launch_bounds__(256) void zero_col0(float* __restrict__ out) {
  int i = blockIdx.x * 256 + threadIdx.x;        // 256,000 float4s total
  int b = i / 8000;
  int r = i - b * 8000;
  f32x4 z = {0.f, 0.f, 0.f, 0.f};
  __builtin_nontemporal_store(z, (f32x4*)out + b * 1024000 + r);
}

__global__ __launch_bounds__(256) void cvt_bf16(const float* __restrict__ in,
                                                unsigned short* __restrict__ o,
                                                int n4) {
  int i = blockIdx.x * 256 + threadIdx.x;
  if (i < n4) {
    float4 v = ((const float4*)in)[i];
    ushort4 u;
    u.x = f2bf(v.x); u.y = f2bf(v.y); u.z = f2bf(v.z); u.w = f2bf(v.w);
    *(ushort4*)(o + i * 4) = u;
  }
}

// Whh[1024 r][256 k] -> f16 T[chunk j][512 tid][8 e], j = gate*16 + kk.
__global__ __launch_bounds__(256) void prep_whalf(const float* __restrict__ We,
                                                  const float* __restrict__ Wd,
                                                  unsigned short* __restrict__ Te,
                                                  unsigned short* __restrict__ Td) {
  int d = blockIdx.x * 256 + threadIdx.x;       // 0..262143
  const float* W = blockIdx.y ? Wd : We;
  unsigned short* T = blockIdx.y ? Td : Te;
  int e = d & 7;
  int tmp = d >> 3;
  int tidb = tmp & 511;
  int j = tmp >> 9;                 // 0..63
  int gg = j >> 4, kk = j & 15;
  int wv = tidb >> 6, ln = tidb & 63;
  int qq = ln >> 5, dm = wv * 32 + (ln & 31);
  _Float16 v = (_Float16)W[(gg * 256 + dm) * 256 + qq * 128 + kk * 8 + e];
  T[d] = __builtin_bit_cast(unsigned short, v);
}

// ---------------------------------------------------------------------------
// xg[row][n] = emb[token(row)] @ Wih^T + bias ; row = t*32 + b
__global__ __launch_bounds__(256) void xg_gemm(
    const int* __restrict__ tok, const float* __restrict__ emb,
    const float* __restrict__ Wih, const float* __restrict__ bias,
    float* __restrict__ xg, const int Mrows) {
  __shared__ unsigned short As[128][264];  // +8 bf16 pad -> 2-way (free)
  __shared__ unsigned short Bs[128][264];
  const int tid = threadIdx.x;
  const int nb = blockIdx.x, rb = blockIdx.y;
  {
    int lr = tid >> 1, half = tid & 1;
    int cb = half * 128;
    int row = rb * 128 + lr;
    int rowc = row < Mrows ? row : (Mrows - 1);
    int tt = rowc >> 5, bb = rowc & 31;
    int tk = tok[bb * 128 + tt];
    const float4* sa = (const float4*)(emb + tk * 256 + cb);
    const float4* sb = (const float4*)(Wih + (nb * 128 + lr) * 256 + cb);
#pragma unroll
    for (int i = 0; i < 32; ++i) {
      float4 v = sa[i];
      ushort4 u;
      u.x = f2bf(v.x); u.y = f2bf(v.y); u.z = f2bf(v.z); u.w = f2bf(v.w);
      *(ushort4*)&As[lr][cb + i * 4] = u;
      float4 v2 = sb[i];
      ushort4 u2;
      u2.x = f2bf(v2.x); u2.y = f2bf(v2.y); u2.z = f2bf(v2.z); u2.w = f2bf(v2.w);
      *(ushort4*)&Bs[lr][cb + i * 4] = u2;
    }
  }
  __syncthreads();
  const int lane = tid & 63, w = tid >> 6;
  const int wr = w >> 1, wc = w & 1;
  const int fr = lane & 15, kg = lane >> 4;
  f32x4 acc[4][4];
  const f32x4 zero = {0.f, 0.f, 0.f, 0.f};
#pragma unroll
  for (int mi = 0; mi < 4; ++mi)
#pragma unroll
    for (int ni = 0; ni < 4; ++ni) acc[mi][ni] = zero;
#pragma unroll
  for (int ks = 0; ks < 8; ++ks) {
    const int kb = ks * 32 + kg * 8;
    bf16x8 a[4], b[4];
#pragma unroll
    for (int mi = 0; mi < 4; ++mi)
      a[mi] = *(const bf16x8*)&As[wr * 64 + mi * 16 + fr][kb];
#pragma unroll
    for (int ni = 0; ni < 4; ++ni)
      b[ni] = *(const bf16x8*)&Bs[wc * 64 + ni * 16 + fr][kb];
#pragma unroll
    for (int mi = 0; mi < 4; ++mi)
#pragma unroll
      for (int ni = 0; ni < 4; ++ni)
        acc[mi][ni] = __builtin_amdgcn_mfma_f32_16x16x32_bf16(a[mi], b[ni], acc[mi][ni], 0, 0, 0);
  }
#pragma unroll
  for (int ni = 0; ni < 4; ++ni) {
    const int colg = nb * 128 + wc * 64 + ni * 16 + fr;
    const float bv = bias[colg];
#pragma unroll
    for (int mi = 0; mi < 4; ++mi) {
#pragma unroll
      for (int r = 0; r < 4; ++r) {
        int rowg = rb * 128 + wr * 64 + mi * 16 + kg * 4 + r;
        if (rowg < Mrows) xg[rowg * 1024 + colg] = acc[mi][ni][r] + bv;
      }
    }
  }
}

// ---------------------------------------------------------------------------
// Fused LSTM producers + FC consumers. 256 blocks x 512 threads, 1 block/CU.
__global__ __launch_bounds__(512, 2) void lstm_fc(
    const unsigned short* __restrict__ WTe, const unsigned short* __restrict__ WTd,
    const float* __restrict__ xgE, const float* __restrict__ xgD,
    unsigned short* __restrict__ hs, const unsigned short* __restrict__ fwb,
    const float* __restrict__ fcb, float* __restrict__ out,
    unsigned* __restrict__ flags) {
  __shared__ __align__(16) char smem[132096];
  __shared__ int curid;
  const int tid = threadIdx.x;   // 0..511
  const int blk = blockIdx.x;
  unsigned* prog = flags;        // [32] chunks published per batch row
  unsigned* ctr = flags + 32;    // work-item counter

  if (blk < 32) {
    // ================= producer: LSTM chain for batch row blk ==============
    unsigned short (*hh)[256] = (unsigned short (*)[256])smem;  // dbuf h f16
    unsigned short* wl = (unsigned short*)(smem + 1024);        // 128 KB o-gate
    const int b = blk;
    const int l = tid & 63, w = tid >> 6;
    const int q = l >> 5;
    const int dim = w * 32 + (l & 31);
    float c = 0.f;
    int cur = 0;
    if (tid < 256) hh[0][tid] = 0;

    for (int phase = 0; phase < 2; ++phase) {
      const unsigned short* WT = phase ? WTd : WTe;
      const float* xg = phase ? xgD : xgE;
      const int steps = phase ? 127 : 128;
      const u16x8* wsrc = (const u16x8*)WT + tid;
      u16x8 wr[KC_REG];
#pragma unroll
      for (int j = 0; j < KC_REG; ++j) wr[j] = wsrc[j * 512];
      __syncthreads();
      {
        u16x8* ld = (u16x8*)wl + tid;
#pragma unroll
        for (int j = 0; j < KC_LDS; ++j) ld[j * 512] = wsrc[(KC_REG + j) * 512];
      }
      __syncthreads();

      for (int t = 0; t < steps; ++t) {
        const float* xr = xg + (t * 32 + b) * 1024 + dim;
        float x0 = xr[0], x1 = xr[256], x2 = xr[512], x3 = xr[768];
        const u32x4* hq = (const u32x4*)&hh[cur][q * 128];
        const u16x8* wlp = (const u16x8*)wl + tid;
        float ai0 = 0.f, ai1 = 0.f, af0 = 0.f, af1 = 0.f;
        float ag0 = 0.f, ag1 = 0.f, ao0 = 0.f, ao1 = 0.f;
#pragma unroll
        for (int kk = 0; kk < 16; ++kk) {
          u32x4 hv = hq[kk];
          dot8(wr[kk],        hv, ai0, ai1);
          dot8(wr[16 + kk],   hv, af0, af1);
          dot8(wr[32 + kk],   hv, ag0, ag1);
          dot8(wlp[kk * 512], hv, ao0, ao1);
        }
        float gi = ai0 + ai1, gf = af0 + af1;
        float gg = ag0 + ag1, go = ao0 + ao1;
        gi += __shfl_xor(gi, 32, 64);
        gf += __shfl_xor(gf, 32, 64);
        gg += __shfl_xor(gg, 32, 64);
        go += __shfl_xor(go, 32, 64);
        gi += x0; gf += x1; gg += x2; go += x3;
        c = sigf(gf) * c + sigf(gi) * tanh_fast(gg);
        float h = sigf(go) * tanh_fast(c);
        if (l < 32) {
          _Float16 hf = (_Float16)h;
          hh[cur ^ 1][dim] = __builtin_bit_cast(unsigned short, hf);
          if (phase) hs[(b * 128 + t) * 256 + dim] = f2bf(h);
        }
        __syncthreads();               // h(t) + hs stores drained (vmcnt 0)
        cur ^= 1;
        if (phase && (((t & 31) == 31) || (t == 126))) {
          if (tid == 0) {
            __threadfence();           // flush hs to device coherence point
            __hip_atomic_store(&prog[b], (unsigned)((t >> 5) + 1),
                               __ATOMIC_RELEASE, __HIP_MEMORY_SCOPE_AGENT);
          }
        }
      }
    }
  }

  // ================= consumer: FC work items (all blocks join) =============
  // item = tc*250 + nb. Stage B (128x256, 64KB) once; loop b=0..31:
  // wait prog[b] > tc, stage A (32x256), MFMA (8 waves: 2m x 4n), store.
  typedef unsigned short usrow[264];
  usrow* Bs = (usrow*)smem;                       // [128][264] @ 0
  usrow* As = (usrow*)(smem + 67584);             // [32][264]
  typedef float frow[132];
  frow* Ct = (frow*)(smem + 84480);               // [32][132]
  const int lane = tid & 63, wv = tid >> 6;
  const int wm = wv & 1, wn = wv >> 1;            // 2 m-tiles x 4 n-tiles
  const int fr = lane & 15, kg = lane >> 4;

  while (true) {
    __syncthreads();                   // protect smem + curid from prev use
    if (tid == 0) {
      curid = (int)__hip_atomic_fetch_add(ctr, 1u, __ATOMIC_RELAXED,
                                          __HIP_MEMORY_SCOPE_AGENT);
    }
    __syncthreads();
    const int id = curid;
    if (id >= N_ITEMS) break;
    const int tc = id / 250;
    const int nb = id - tc * 250;
    const unsigned need = (unsigned)(tc + 1);
    {                                  // stage B tile once per item
      int row = tid >> 2, sg = tid & 3;
      const u16x8* s = (const u16x8*)(fwb + (nb * 128 + row) * 256 + sg * 64);
      u16x8* d = (u16x8*)&Bs[row][sg * 64];
#pragma unroll
      for (int i = 0; i < 8; ++i) d[i] = s[i];
    }

    for (int b = 0; b < 32; ++b) {
      if (tid == 0) {
        while (__hip_atomic_load(&prog[b], __ATOMIC_RELAXED,
                                 __HIP_MEMORY_SCOPE_AGENT) < need)
          __builtin_amdgcn_s_sleep(8);
        (void)__hip_atomic_load(&prog[b], __ATOMIC_ACQUIRE,
                                __HIP_MEMORY_SCOPE_AGENT);
      }
      __syncthreads();                 // hs chunk visible; prev stores done
      {                                // stage A (32 rows x 256)
        int ar = tid >> 4, ac = (tid & 15) * 16;
        const u16x8* s2 =
            (const u16x8*)(hs + (b * 128 + tc * 32 + ar) * 256 + ac);
        u16x8* d2 = (u16x8*)&As[ar][ac];
        d2[0] = s2[0]; d2[1] = s2[1];
      }
      __syncthreads();                 // As ready (Bs ready since item start)
      f32x4 acc[2];
      const f32x4 zero = {0.f, 0.f, 0.f, 0.f};
      acc[0] = zero; acc[1] = zero;
#pragma unroll
      for (int ks = 0; ks < 8; ++ks) {
        const int kb = ks * 32 + kg * 8;
        bf16x8 a = *(const bf16x8*)&As[wm * 16 + fr][kb];
        bf16x8 b0 = *(const bf16x8*)&Bs[wn * 32 + fr][kb];
        bf16x8 b1 = *(const bf16x8*)&Bs[wn * 32 + 16 + fr][kb];
        acc[0] = __builtin_amdgcn_mfma_f32_16x16x32_bf16(a, b0, acc[0], 0, 0, 0);
        acc[1] = __builtin_amdgcn_mfma_f32_16x16x32_bf16(a, b1, acc[1], 0, 0, 0);
      }
#pragma unroll
      for (int ni = 0; ni < 2; ++ni) { // epilogue -> Ct (separate region)
        const int cl = wn * 32 + ni * 16 + fr;
        const float bv = fcb[nb * 128 + cl];
#pragma unroll
        for (int r = 0; r < 4; ++r)
          Ct[wm * 16 + kg * 4 + r][cl] = acc[ni][r] + bv;
      }
      __syncthreads();                 // Ct complete
      {                                // full-sector nt stores:
        // pass p: row = p*16 + (tid>>5), cc = (tid&31)*4 -> each wave inst
        // covers 2 rows x 512B fully-contiguous.
        const int rr = tid >> 5, cc = (tid & 31) * 4;
#pragma unroll
        for (int p = 0; p < 2; ++p) {
          int r = p * 16 + rr;
          int tg = tc * 32 + r;
          if (tg != 127) {             // t=127 is padding
            float* dst =
                out + (size_t)(b * 128 + tg + 1) * 32000 + nb * 128 + cc;
            f32x4 v = *(const f32x4*)&Ct[r][cc];
            __builtin_nontemporal_store(v, (f32x4*)dst);
          }
        }
      }
      __syncthreads();                 // stores read Ct before next overwrite
    }
  }
}

// ---------------------------------------------------------------------------
extern "C" void kernel_launch(void* const* d_in, const int* in_sizes, int n_in,
                              void* d_out, int out_size, void* d_ws, size_t ws_size,
                              hipStream_t stream) {
  const int* src = (const int*)d_in[0];
  const int* tgt = (const int*)d_in[1];
  const float* enc_emb = (const float*)d_in[2];
  const float* enc_Wih = (const float*)d_in[3];
  const float* enc_Whh = (const float*)d_in[4];
  const float* enc_b = (const float*)d_in[5];
  const float* dec_emb = (const float*)d_in[6];
  const float* dec_Wih = (const float*)d_in[7];
  const float* dec_Whh = (const float*)d_in[8];
  const float* dec_b = (const float*)d_in[9];
  const float* fc_W = (const float*)d_in[10];
  const float* fc_b = (const float*)d_in[11];
  float* out = (float*)d_out;
  char* ws = (char*)d_ws;

  float* xg_e = (float*)(ws + WS_XG_E);
  float* xg_d = (float*)(ws + WS_XG_D);
  unsigned short* fcw = (unsigned short*)(ws + WS_FCW);
  unsigned short* hs = (unsigned short*)(ws + WS_HS);
  unsigned short* wte = (unsigned short*)(ws + WS_WTE);
  unsigned short* wtd = (unsigned short*)(ws + WS_WTD);
  unsigned* flags = (unsigned*)(ws + WS_FLAGS);

  hipMemsetAsync(ws + WS_FLAGS, 0, 256, stream);   // prog[32] + ctr = 0
  zero_col0<<<1000, 256, 0, stream>>>(out);
  cvt_bf16<<<8000, 256, 0, stream>>>(fc_W, fcw, 2048000);
  prep_whalf<<<dim3(1024, 2), 256, 0, stream>>>(enc_Whh, dec_Whh, wte, wtd);
  xg_gemm<<<dim3(8, 32), 256, 0, stream>>>(src, enc_emb, enc_Wih, enc_b, xg_e, 4096);
  xg_gemm<<<dim3(8, 32), 256, 0, stream>>>(tgt, dec_emb, dec_Wih, dec_b, xg_d, 4064);
  lstm_fc<<<256, 512, 0, stream>>>(wte, wtd, xg_e, xg_d, hs, fcw, fc_b, out, flags);
}